// Round 4
// baseline (699.594 us; speedup 1.0000x reference)
//
#include <hip/hip_runtime.h>
#include <math.h>

#define BB 8
#define NN 2048
#define DD 256
#define KK 100
#define RR 5
#define BIGV 1000000000.0f
#define LN_EPS 1e-5f

typedef __attribute__((ext_vector_type(8))) short short8;
typedef __attribute__((ext_vector_type(4))) float floatx4;

// ---------------------------------------------------------------------------
// bf16 helpers
// ---------------------------------------------------------------------------
__device__ static inline unsigned short f2bf_rne(float x) {
  unsigned int u = __float_as_uint(x);
  unsigned int r = (u + 0x7FFFu + ((u >> 16) & 1u)) >> 16;
  return (unsigned short)r;
}
__device__ static inline float bf2f(unsigned short h) {
  return __uint_as_float(((unsigned int)h) << 16);
}

__device__ static inline void gl_lds16(const unsigned short* g, unsigned short* l) {
  __builtin_amdgcn_global_load_lds(
      (const __attribute__((address_space(1))) unsigned int*)(g),
      (__attribute__((address_space(3))) unsigned int*)(l), 16, 0, 0);
}

// ---------------------------------------------------------------------------
// Kernel 0: split q,k (fp32) into bf16 hi/lo planes.
// ---------------------------------------------------------------------------
__global__ __launch_bounds__(256) void split_bf16(const float* __restrict__ q,
                                                  const float* __restrict__ k,
                                                  ushort4* __restrict__ qhi,
                                                  ushort4* __restrict__ qlo,
                                                  ushort4* __restrict__ khi,
                                                  ushort4* __restrict__ klo) {
  const int n4 = BB * NN * DD / 4;
  const float4* src = (blockIdx.y == 0) ? (const float4*)q : (const float4*)k;
  ushort4* hi = blockIdx.y ? khi : qhi;
  ushort4* lo = blockIdx.y ? klo : qlo;
  for (int i = blockIdx.x * 256 + threadIdx.x; i < n4; i += gridDim.x * 256) {
    float4 v = src[i];
    ushort4 h, l;
    h.x = f2bf_rne(v.x); l.x = f2bf_rne(v.x - bf2f(h.x));
    h.y = f2bf_rne(v.y); l.y = f2bf_rne(v.y - bf2f(h.y));
    h.z = f2bf_rne(v.z); l.z = f2bf_rne(v.z - bf2f(h.z));
    h.w = f2bf_rne(v.w); l.w = f2bf_rne(v.w - bf2f(h.w));
    hi[i] = h; lo[i] = l;
  }
}

// ---------------------------------------------------------------------------
// Kernel 1: fused logits + row softmax. One block owns 32 rows x ALL 2048
// cols, so softmax (true max) is block-local and probs are written ONCE.
// 512 threads = 8 waves: wy=w&1 picks row-tile (16 rows), wg=w>>1 picks
// col-tile subset. Col chunks of 256; BK=32; 3-term bf16 split MFMA.
// acc: 32 tiles (16x16) x 4 regs = 128 VGPR/thread.
// Block swizzle: batch = blockIdx.x % 8 -> each XCD (round-robin dispatch)
// keeps one batch's K-planes (4 MB) resident in its L2.
// ---------------------------------------------------------------------------
__global__ __launch_bounds__(512) void gemm_softmax(
    const unsigned short* __restrict__ qhi, const unsigned short* __restrict__ qlo,
    const unsigned short* __restrict__ khi, const unsigned short* __restrict__ klo,
    float* __restrict__ s) {
  __shared__ unsigned short ldsA[2][2][512];   // [row-tile][plane] 1KB frag-tiles
  __shared__ unsigned short ldsB[16][2][512];  // [col-tile][plane]
  __shared__ float red[2][16][4];              // [wy][row-in-tile][wave-group]

  const int t = threadIdx.x;
  const int w = t >> 6, L = t & 63;
  const int wy = w & 1, wg = w >> 1;
  const int q_ = L >> 4, m_ = L & 15;
  const int b = blockIdx.x & 7;
  const int i0 = (blockIdx.x >> 3) * 32;

  const size_t bofs = (size_t)b * NN * DD;
  const unsigned short* qh = qhi + bofs;
  const unsigned short* ql = qlo + bofs;
  const unsigned short* kh = khi + bofs;
  const unsigned short* kl = klo + bofs;

  floatx4 acc[32];
#pragma unroll
  for (int i = 0; i < 32; ++i) acc[i] = (floatx4){0.f, 0.f, 0.f, 0.f};

  for (int ch = 0; ch < 8; ++ch) {
    const int c0 = ch * 256;
    for (int ks = 0; ks < 8; ++ks) {
      const int kb0 = ks * 32;
      // stage 36 frag-tiles (4 A + 32 B), wave w takes T = w, w+8, ...
#pragma unroll
      for (int r = 0; r < 5; ++r) {
        int T = w + 8 * r;
        if (T < 36) {
          const unsigned short* gp;
          unsigned short* dst;
          if (T < 4) {
            int a = T >> 1, p = T & 1;
            const unsigned short* base = p ? ql : qh;
            gp = base + (size_t)(i0 + a * 16 + m_) * DD + kb0 + q_ * 8;
            dst = &ldsA[a][p][0];
          } else {
            int Tb = T - 4;
            int c = Tb >> 1, p = Tb & 1;
            const unsigned short* base = p ? kl : kh;
            gp = base + (size_t)(c0 + c * 16 + m_) * DD + kb0 + q_ * 8;
            dst = &ldsB[c][p][0];
          }
          gl_lds16(gp, dst);
        }
      }
      __syncthreads();

      short8 ah = *(const short8*)&ldsA[wy][0][L * 8];
      short8 al = *(const short8*)&ldsA[wy][1][L * 8];
#pragma unroll
      for (int i = 0; i < 4; ++i) {
        int c = wg * 4 + i;
        short8 bh = *(const short8*)&ldsB[c][0][L * 8];
        short8 bl = *(const short8*)&ldsB[c][1][L * 8];
        int ai = ch * 4 + i;
        acc[ai] = __builtin_amdgcn_mfma_f32_16x16x32_bf16(ah, bh, acc[ai], 0, 0, 0);
        acc[ai] = __builtin_amdgcn_mfma_f32_16x16x32_bf16(ah, bl, acc[ai], 0, 0, 0);
        acc[ai] = __builtin_amdgcn_mfma_f32_16x16x32_bf16(al, bh, acc[ai], 0, 0, 0);
      }
      __syncthreads();
    }
  }

  // ---- softmax epilogue. Lane holds rows (q_*4+r) of row-tile wy across
  // 512 cols (32 tiles x 16 lanes); full row needs shfl over 16-lane col
  // group + LDS reduce over the 4 wave-groups.
  float rmax[4];
#pragma unroll
  for (int r = 0; r < 4; ++r) {
    float m = -3.4e38f;
#pragma unroll
    for (int i = 0; i < 32; ++i) m = fmaxf(m, acc[i][r]);
    rmax[r] = m;
  }
#pragma unroll
  for (int off = 8; off; off >>= 1)
#pragma unroll
    for (int r = 0; r < 4; ++r) rmax[r] = fmaxf(rmax[r], __shfl_xor(rmax[r], off));
  if (m_ == 0)
#pragma unroll
    for (int r = 0; r < 4; ++r) red[wy][q_ * 4 + r][wg] = rmax[r];
  __syncthreads();
  float M[4];
#pragma unroll
  for (int r = 0; r < 4; ++r) {
    int ri = q_ * 4 + r;
    M[r] = fmaxf(fmaxf(red[wy][ri][0], red[wy][ri][1]),
                 fmaxf(red[wy][ri][2], red[wy][ri][3]));
  }
  __syncthreads();

  float rsum[4] = {0.f, 0.f, 0.f, 0.f};
#pragma unroll
  for (int i = 0; i < 32; ++i)
#pragma unroll
    for (int r = 0; r < 4; ++r) {
      float e = expf(acc[i][r] - M[r]);
      acc[i][r] = e;
      rsum[r] += e;
    }
#pragma unroll
  for (int off = 8; off; off >>= 1)
#pragma unroll
    for (int r = 0; r < 4; ++r) rsum[r] += __shfl_xor(rsum[r], off);
  if (m_ == 0)
#pragma unroll
    for (int r = 0; r < 4; ++r) red[wy][q_ * 4 + r][wg] = rsum[r];
  __syncthreads();
  float inv[4];
#pragma unroll
  for (int r = 0; r < 4; ++r) {
    int ri = q_ * 4 + r;
    inv[r] = 1.0f / (red[wy][ri][0] + red[wy][ri][1] + red[wy][ri][2] + red[wy][ri][3]);
  }

  // C/D layout: col = lane&15, row = q_*4 + reg
#pragma unroll
  for (int ch = 0; ch < 8; ++ch)
#pragma unroll
    for (int i = 0; i < 4; ++i) {
      int col = (ch * 16 + wg * 4 + i) * 16 + m_;
#pragma unroll
      for (int r = 0; r < 4; ++r) {
        int row = i0 + wy * 16 + q_ * 4 + r;
        s[((size_t)b * NN + row) * NN + col] = acc[ch * 4 + i][r] * inv[r];
      }
    }
}

// ---------------------------------------------------------------------------
// Fallback fp32 GEMM + separate softmax (only if ws too small for splits).
// ---------------------------------------------------------------------------
__global__ __launch_bounds__(256) void gemm_logits(const float* __restrict__ q,
                                                   const float* __restrict__ k,
                                                   float* __restrict__ s) {
  __shared__ float As[32][132];
  __shared__ float Bs[32][132];
  const int b = blockIdx.z;
  const int i0 = blockIdx.y * 128;
  const int j0 = blockIdx.x * 128;
  const int t = threadIdx.x;
  const int tx = t & 15;
  const int ty = t >> 4;
  const float* qb = q + (size_t)b * NN * DD;
  const float* kb = k + (size_t)b * NN * DD;

  float acc[8][8];
#pragma unroll
  for (int i = 0; i < 8; ++i)
#pragma unroll
    for (int j = 0; j < 8; ++j) acc[i][j] = 0.f;

  for (int kb0 = 0; kb0 < DD; kb0 += 32) {
#pragma unroll
    for (int l = 0; l < 4; ++l) {
      int f = l * 256 + t;
      int row = f >> 3;
      int c4 = (f & 7) * 4;
      float4 va = *(const float4*)(qb + (size_t)(i0 + row) * DD + kb0 + c4);
      float4 vb = *(const float4*)(kb + (size_t)(j0 + row) * DD + kb0 + c4);
      As[c4 + 0][row] = va.x; As[c4 + 1][row] = va.y;
      As[c4 + 2][row] = va.z; As[c4 + 3][row] = va.w;
      Bs[c4 + 0][row] = vb.x; Bs[c4 + 1][row] = vb.y;
      Bs[c4 + 2][row] = vb.z; Bs[c4 + 3][row] = vb.w;
    }
    __syncthreads();
#pragma unroll
    for (int kk = 0; kk < 32; ++kk) {
      float a[8], bv[8];
      *(float4*)&a[0] = *(const float4*)&As[kk][ty * 8];
      *(float4*)&a[4] = *(const float4*)&As[kk][ty * 8 + 4];
      *(float4*)&bv[0] = *(const float4*)&Bs[kk][tx * 8];
      *(float4*)&bv[4] = *(const float4*)&Bs[kk][tx * 8 + 4];
#pragma unroll
      for (int i = 0; i < 8; ++i)
#pragma unroll
        for (int j = 0; j < 8; ++j) acc[i][j] += a[i] * bv[j];
    }
    __syncthreads();
  }

#pragma unroll
  for (int i = 0; i < 8; ++i) {
    size_t row = (size_t)(i0 + ty * 8 + i);
    float* po = s + ((size_t)b * NN + row) * NN + j0 + tx * 8;
    *(float4*)po = make_float4(acc[i][0], acc[i][1], acc[i][2], acc[i][3]);
    *(float4*)(po + 4) = make_float4(acc[i][4], acc[i][5], acc[i][6], acc[i][7]);
  }
}

__global__ __launch_bounds__(256) void softmax_rows(float* __restrict__ s) {
  const int bi = blockIdx.x;
  const int t = threadIdx.x;
  float4* rowp = (float4*)(s + (size_t)bi * NN);
  float4 v0 = rowp[t];
  float4 v1 = rowp[256 + t];

  __shared__ float red[4];
  float m = fmaxf(fmaxf(fmaxf(v0.x, v0.y), fmaxf(v0.z, v0.w)),
                  fmaxf(fmaxf(v1.x, v1.y), fmaxf(v1.z, v1.w)));
#pragma unroll
  for (int off = 32; off; off >>= 1) m = fmaxf(m, __shfl_xor(m, off));
  if ((t & 63) == 0) red[t >> 6] = m;
  __syncthreads();
  m = fmaxf(fmaxf(red[0], red[1]), fmaxf(red[2], red[3]));
  __syncthreads();

  float4 e0, e1;
  e0.x = expf(v0.x - m); e0.y = expf(v0.y - m);
  e0.z = expf(v0.z - m); e0.w = expf(v0.w - m);
  e1.x = expf(v1.x - m); e1.y = expf(v1.y - m);
  e1.z = expf(v1.z - m); e1.w = expf(v1.w - m);
  float sum = e0.x + e0.y + e0.z + e0.w + e1.x + e1.y + e1.z + e1.w;
#pragma unroll
  for (int off = 32; off; off >>= 1) sum += __shfl_xor(sum, off);
  if ((t & 63) == 0) red[t >> 6] = sum;
  __syncthreads();
  sum = red[0] + red[1] + red[2] + red[3];

  float inv = 1.0f / sum;
  rowp[t] = make_float4(e0.x * inv, e0.y * inv, e0.z * inv, e0.w * inv);
  rowp[256 + t] = make_float4(e1.x * inv, e1.y * inv, e1.z * inv, e1.w * inv);
}

// ---------------------------------------------------------------------------
// Kernel 3: top-100 of diag per batch; diag gathered straight from s.
// ---------------------------------------------------------------------------
__global__ __launch_bounds__(1024) void topk_diag(const float* __restrict__ s,
                                                  int* __restrict__ topidx) {
  const int b = blockIdx.x;
  const int t = threadIdx.x;
  __shared__ unsigned long long key[NN];
  __shared__ int idxs[KK];

#pragma unroll
  for (int sIt = 0; sIt < 2; ++sIt) {
    int i = t + sIt * 1024;
    unsigned int vb = __float_as_uint(s[((size_t)b * NN + i) * NN + i]);
    key[i] = ((unsigned long long)vb << 32) | (unsigned int)(NN - 1 - i);
  }
  __syncthreads();

  for (int kstep = 2; kstep <= NN; kstep <<= 1) {
    for (int j = kstep >> 1; j > 0; j >>= 1) {
      int i = ((t & ~(j - 1)) << 1) | (t & (j - 1));
      int l = i | j;
      unsigned long long a = key[i];
      unsigned long long c = key[l];
      bool desc = ((i & kstep) == 0);
      if (desc ? (a < c) : (a > c)) { key[i] = c; key[l] = a; }
      __syncthreads();
    }
  }

  if (t < KK) idxs[t] = NN - 1 - (int)(unsigned int)(key[t] & 0xFFFFFFFFu);
  __syncthreads();
  if (t < KK) {
    int myidx = idxs[t];
    int rank = 0;
#pragma unroll 4
    for (int j = 0; j < KK; ++j) rank += (idxs[j] < myidx) ? 1 : 0;
    topidx[b * KK + rank] = myidx;
  }
}

// ---------------------------------------------------------------------------
// Kernel 4: gather rel (100x100) into LDS cooperatively, then per-row top-5.
// ---------------------------------------------------------------------------
__global__ __launch_bounds__(256) void rel_topk(const float* __restrict__ s,
                                                const int* __restrict__ topidx,
                                                float* __restrict__ soi,
                                                int2* __restrict__ pairs) {
  const int b = blockIdx.x;
  const int t = threadIdx.x;
  __shared__ int tix[KK];
  __shared__ float rel[KK][KK + 1];
  if (t < KK) tix[t] = topidx[b * KK + t];
  __syncthreads();

  for (int e = t; e < KK * KK; e += 256) {
    int i = e / KK;
    int j = e - i * KK;
    rel[i][j] = (i == j) ? BIGV : s[((size_t)b * NN + tix[i]) * NN + tix[j]];
  }
  __syncthreads();

  if (t < KK) {
    int sel[RR];
#pragma unroll
    for (int r = 0; r < RR; ++r) sel[r] = -1;
#pragma unroll
    for (int r = 0; r < RR; ++r) {
      float best = -2.f;
      int bj = -1;
      for (int j = 0; j < KK; ++j) {
        bool taken = false;
#pragma unroll
        for (int sN = 0; sN < RR; ++sN)
          if (sN < r && sel[sN] == j) taken = true;
        if (taken) continue;
        float v = rel[t][j];
        if (v > best) { best = v; bj = j; }
      }
      sel[r] = bj;
    }
#pragma unroll
    for (int a2 = 0; a2 < RR; ++a2)
#pragma unroll
      for (int b2 = a2 + 1; b2 < RR; ++b2)
        if (sel[b2] < sel[a2]) { int tmp = sel[a2]; sel[a2] = sel[b2]; sel[b2] = tmp; }

    int subj = tix[t];
#pragma unroll
    for (int r = 0; r < RR; ++r) {
      int obj = tix[sel[r]];
      size_t p = ((size_t)b * KK + t) * RR + r;
      soi[p * 3 + 0] = (float)b;
      soi[p * 3 + 1] = (float)subj;
      soi[p * 3 + 2] = (float)obj;
      pairs[p] = make_int2(subj, obj);
    }
  }
}

// ---------------------------------------------------------------------------
// Kernel 5: re = layernorm(q[b,subj] + q[b,obj]) over D=256.
// ---------------------------------------------------------------------------
__global__ __launch_bounds__(64) void edge_ln(const float* __restrict__ q,
                                              const int2* __restrict__ pairs,
                                              float* __restrict__ re) {
  const int p = blockIdx.x;
  const int b = p / (KK * RR);
  const int l = threadIdx.x;
  int2 pr = pairs[p];
  const float4* qs = (const float4*)(q + ((size_t)b * NN + pr.x) * DD);
  const float4* qo = (const float4*)(q + ((size_t)b * NN + pr.y) * DD);
  float4 a = qs[l];
  float4 o = qo[l];
  a.x += o.x; a.y += o.y; a.z += o.z; a.w += o.w;
  float sum = a.x + a.y + a.z + a.w;
  float sq = a.x * a.x + a.y * a.y + a.z * a.z + a.w * a.w;
#pragma unroll
  for (int off = 32; off; off >>= 1) {
    sum += __shfl_xor(sum, off);
    sq += __shfl_xor(sq, off);
  }
  float mu = sum * (1.f / DD);
  float var = sq * (1.f / DD) - mu * mu;
  float rs = rsqrtf(var + LN_EPS);
  float4 r4 = make_float4((a.x - mu) * rs, (a.y - mu) * rs,
                          (a.z - mu) * rs, (a.w - mu) * rs);
  ((float4*)(re + (size_t)p * DD))[l] = r4;
}

// ---------------------------------------------------------------------------
extern "C" void kernel_launch(void* const* d_in, const int* in_sizes, int n_in,
                              void* d_out, int out_size, void* d_ws, size_t ws_size,
                              hipStream_t stream) {
  const float* q = (const float*)d_in[0];
  const float* k = (const float*)d_in[1];

  float* out = (float*)d_out;
  float* scores = out;
  float* soi = out + (size_t)BB * NN * NN;
  float* re = soi + (size_t)BB * KK * RR * 3;

  char* ws = (char*)d_ws;
  int* topidx = (int*)ws;
  int2* pairs = (int2*)(ws + 64 * 1024);
  const size_t small_end = 128 * 1024;
  const size_t plane = (size_t)BB * NN * DD * 2;  // 8 MiB per bf16 plane
  const bool use_mfma = ws_size >= small_end + 4 * plane;

  if (use_mfma) {
    unsigned short* qhi = (unsigned short*)(ws + small_end);
    unsigned short* qlo = (unsigned short*)(ws + small_end + plane);
    unsigned short* khi = (unsigned short*)(ws + small_end + 2 * plane);
    unsigned short* klo = (unsigned short*)(ws + small_end + 3 * plane);
    split_bf16<<<dim3(1024, 2), 256, 0, stream>>>(q, k, (ushort4*)qhi, (ushort4*)qlo,
                                                  (ushort4*)khi, (ushort4*)klo);
    gemm_softmax<<<dim3(BB * NN / 32), 512, 0, stream>>>(qhi, qlo, khi, klo, scores);
  } else {
    gemm_logits<<<dim3(NN / 128, NN / 128, BB), 256, 0, stream>>>(q, k, scores);
    softmax_rows<<<dim3(BB * NN), 256, 0, stream>>>(scores);
  }
  topk_diag<<<dim3(BB), 1024, 0, stream>>>(scores, topidx);
  rel_topk<<<dim3(BB), 256, 0, stream>>>(scores, topidx, soi, pairs);
  edge_ln<<<dim3(BB * KK * RR), 64, 0, stream>>>(q, pairs, re);
}